// Round 14
// baseline (33.979 us; speedup 1.0000x reference)
//
#include <hip/hip_runtime.h>

// Denoiser MLP (2->16, 5x 16->16, 16->2), fp32 in/out, via v_mfma_f32_32x32x16_f16.
// R14: register-pressure reduction -> sequential streams.
// Evidence: dur ~= VALUbusy + MFMAbusy (no overlap) and occupancy 2.6
// waves/SIMD despite lb(256,4) + VGPR_Count 44-56 => large hidden AGPR
// allocation (unified-RF total >128) causing both the occupancy cap and
// v_accvgpr_read/write shuttle traffic (~250 extra VALU/body). Fix: process
// the two 32-pt streams SEQUENTIALLY so only ONE 16-reg D-tuple is live at a
// time; peak ~80 regs < 128 budget -> allocator has no reason to touch AGPRs.
// R12/R13 lesson: no raw VOP3P/MFMA inline asm (hazards/encodings unverified).
//
// Mapping (verified R6-R11, absmax 7.8e-3):
//   A (32x16) = [W; W], B (16x32) = 32 points' features (transposed)
//   A frag: lane l holds A[i=l&31][k=8*(l>>5)+j]
//   B frag: lane l holds B[k=8*(l>>5)+j][n=l&31]
//   D frag: lane l holds D[i=(reg&3)+8*(reg>>2)+4*(l>>5)][n=l&31]
// D regs 0-7 at hi=l>>5 = rows {0-3,8-11}/{4-7,12-15}; next-layer weights
// column-permuted [0-3,8-11 | 4-7,12-15] -> layers chain in register order.
// Input trick: bin = pack4(cvtpk(x,y),0,0,0); wi0 (W at k0,1) computes hi=0
// lanes' points (stream0 = pts base+0..31), wi1 (W at k8,9) hi=1 lanes'
// (stream1 = pts base+32..63). bin stays live across stream0's chain.

typedef _Float16 h8 __attribute__((ext_vector_type(8)));
typedef float f16v __attribute__((ext_vector_type(16)));
typedef float f4 __attribute__((ext_vector_type(4)));
typedef float f2 __attribute__((ext_vector_type(2)));
typedef unsigned int u32;
typedef u32 u4v __attribute__((ext_vector_type(4)));

static __device__ __forceinline__ f16v mfma32(h8 a, h8 b, f16v c) {
    return __builtin_amdgcn_mfma_f32_32x32x16_f16(a, b, c, 0, 0, 0);
}

static __device__ __forceinline__ u32 cvtpk(float a, float b) {
    return __builtin_bit_cast(u32, __builtin_amdgcn_cvt_pkrtz(a, b));
}

static __device__ __forceinline__ h8 pack4(u32 a, u32 b, u32 c, u32 d) {
    u4v p = {a, b, c, d};
    return __builtin_bit_cast(h8, p);
}

// quad-permuted weight fragment: j0-3 = cols 4*hi.., j4-7 = cols 8+4*hi..
static __device__ __forceinline__ h8 wfrag(const float* row, int hi) {
    const f4* r4 = (const f4*)row;
    f4 q0 = r4[hi], q1 = r4[hi + 2];
    return pack4(cvtpk(q0.x, q0.y), cvtpk(q0.z, q0.w),
                 cvtpk(q1.x, q1.y), cvtpk(q1.z, q1.w));
}

// relu + cvt of D regs 0-7 -> next layer's B fragment (order-preserving)
static __device__ __forceinline__ h8 cvt_relu8(f16v a) {
    h8 hb = pack4(cvtpk(a[0], a[1]), cvtpk(a[2], a[3]),
                  cvtpk(a[4], a[5]), cvtpk(a[6], a[7]));
    const h8 z = {};
    return __builtin_elementwise_max(hb, z);
}

__global__ __launch_bounds__(256, 4) void denoiser_mfma32(
    const f2* __restrict__ x,        // [N] points (x0,x1)
    const float* __restrict__ w_in,  // [16][2]
    const float* __restrict__ w_mid, // [5][16][16]
    const float* __restrict__ w_out, // [2][16]
    f2* __restrict__ out,            // [N] (o0,o1)
    int n)
{
    const int lane = threadIdx.x & 63;
    const int m    = lane & 15;   // weight row (rows duplicated mod 16)
    const int hi   = lane >> 5;   // half-wave / k-group
    const int wave = threadIdx.x >> 6;

    const h8 hz = {};

    // ---- one-time weight fragments ----
    u32 wxy = cvtpk(w_in[2 * m], w_in[2 * m + 1]);
    h8 wi0 = hi == 0 ? pack4(wxy, 0u, 0u, 0u) : hz;   // stream0: pts 0..31
    h8 wi1 = hi == 1 ? pack4(wxy, 0u, 0u, 0u) : hz;   // stream1: pts 32..63

    h8 wm0 = wfrag(w_mid + 0 * 256 + m * 16, hi);
    h8 wm1 = wfrag(w_mid + 1 * 256 + m * 16, hi);
    h8 wm2 = wfrag(w_mid + 2 * 256 + m * 16, hi);
    h8 wm3 = wfrag(w_mid + 3 * 256 + m * 16, hi);
    h8 wm4 = wfrag(w_mid + 4 * 256 + m * 16, hi);

    h8 wo = m < 2 ? wfrag(w_out + m * 16, hi) : hz;

    // one-time pin: zero C-operand stays resident, un-rematerializable
    f16v z16 = {};
    asm("" : "+v"(z16));

    const int nchunks = (n + 255) >> 8;     // 256-pt block chunks
    const int stride  = gridDim.x;
    const int nm1     = n - 1;

    auto loadx = [&](int c) -> f2 {
        int pi = c * 256 + wave * 64 + lane;
        return x[pi < n ? pi : nm1];
    };

    // one 32-pt stream: input MFMA (selected by wi variant), 5 mid layers,
    // output MFMA, store. Only ONE 16-reg D-tuple live at any moment.
    auto stream = [&](h8 wi, h8 bin, int sbase) {
        f16v a = mfma32(wi, bin, z16);
        h8 b = cvt_relu8(a);
        a = mfma32(wm0, b, z16);  b = cvt_relu8(a);
        a = mfma32(wm1, b, z16);  b = cvt_relu8(a);
        a = mfma32(wm2, b, z16);  b = cvt_relu8(a);
        a = mfma32(wm3, b, z16);  b = cvt_relu8(a);
        a = mfma32(wm4, b, z16);  b = cvt_relu8(a);
        a = mfma32(wo, b, z16);

        if (lane < 32) {
            int p0 = sbase + lane;
            if (p0 < n) out[p0] = (f2){a[0], a[1]};
        }
    };

    auto body = [&](int c, f2 xy) {
        const int base = c * 256 + wave * 64;
        h8 bin = pack4(cvtpk(xy.x, xy.y), 0u, 0u, 0u);
        stream(wi0, bin, base);        // pts base+ 0..31 (hi=0 lanes' data)
        stream(wi1, bin, base + 32);   // pts base+32..63 (hi=1 lanes' data)
    };

    // ---- depth-2 software pipeline over the grid-stride loop ----
    int c = blockIdx.x;
    f2 xyA = loadx(c);
    f2 xyB = loadx(c + stride < nchunks ? c + stride : c);

    for (; c < nchunks; c += 2 * stride) {
        const int cB  = c + stride;
        const int cA2 = c + 2 * stride;
        const int cB2 = c + 3 * stride;

        f2 xyA2 = loadx(cA2 < nchunks ? cA2 : c);
        f2 xyB2 = loadx(cB2 < nchunks ? cB2 : c);

        body(c, xyA);
        if (cB < nchunks) body(cB, xyB);

        xyA = xyA2;
        xyB = xyB2;
    }
}

extern "C" void kernel_launch(void* const* d_in, const int* in_sizes, int n_in,
                              void* d_out, int out_size, void* d_ws, size_t ws_size,
                              hipStream_t stream) {
    const float* x     = (const float*)d_in[0];
    const float* w_in  = (const float*)d_in[1];
    const float* w_mid = (const float*)d_in[2];
    const float* w_out = (const float*)d_in[3];

    int n = in_sizes[0] / 2;          // number of points
    int nchunks = (n + 255) / 256;
    int blocks = nchunks < 2048 ? nchunks : 2048;  // persistent

    denoiser_mfma32<<<blocks, 256, 0, stream>>>(
        (const f2*)x, w_in, w_mid, w_out, (f2*)d_out, n);
}